// Round 4
// baseline (4458.497 us; speedup 1.0000x reference)
//
#include <hip/hip_runtime.h>
#include <math.h>

#define BATCH 32768
#define MELEM 1024
#define NSWEEP_BATCH 7
#define NSWEEP_PREP 8
#define MPW 4                    // matrix-PAIRS per wave
#define NW (BATCH / (2 * MPW))   // 4096 waves in batch passes
#define NBLK (NW / 4)            // 1024 blocks (4 waves/block)
#define G0 512                   // blocks for partial-mean passes
#define EPSF 1e-5f

// ws layout (float offsets)
#define WS_M0    0
#define WS_MS0   1024
#define WS_MIS0  2048
#define WS_T     3072
#define WS_MIS1  4096
#define WS_P     5120
#define WS_D2    5184            // NW floats
#define WS_PART2 16384           // 512*1024 floats (t-reduction partials)
#define WS_NEED_BIG ((WS_PART2 + G0 * MELEM) * sizeof(float))

// per-wave LDS stage: union of X[2][1024] and Gt[2][32][36] (wt folded at col 32)
#define GT_LD 36
#define GT_H 1152                // 32*36
#define STG_F 2304               // floats per wave

// ---------------- register helpers ----------------

__device__ __forceinline__ float colnorm(const float (&col)[32]) {
    float a0 = 0, a1 = 0, a2 = 0, a3 = 0;
#pragma unroll
    for (int k = 0; k < 32; k += 4) {
        a0 = fmaf(col[k], col[k], a0);
        a1 = fmaf(col[k + 1], col[k + 1], a1);
        a2 = fmaf(col[k + 2], col[k + 2], a2);
        a3 = fmaf(col[k + 3], col[k + 3], a3);
    }
    return (a0 + a1) + (a2 + a3);
}

// One-sided (Hestenes) Jacobi, fixed sweep count (validated in round 2).
// Lane (h,c) owns column c. XOR ordering: round m pairs c with c^m.
__device__ __forceinline__ void onesided_sweeps(float (&col)[32], float &nrm, int nsweeps) {
    for (int sw = 0; sw < nsweeps; ++sw) {
        for (int m = 1; m < 32; ++m) {
            float t[32];
            float npart = __shfl_xor(nrm, m);
            float a0 = 0, a1 = 0, a2 = 0, a3 = 0;
#pragma unroll
            for (int k = 0; k < 32; k += 4) {
                t[k] = __shfl_xor(col[k], m);
                t[k + 1] = __shfl_xor(col[k + 1], m);
                t[k + 2] = __shfl_xor(col[k + 2], m);
                t[k + 3] = __shfl_xor(col[k + 3], m);
                a0 = fmaf(col[k], t[k], a0);
                a1 = fmaf(col[k + 1], t[k + 1], a1);
                a2 = fmaf(col[k + 2], t[k + 2], a2);
                a3 = fmaf(col[k + 3], t[k + 3], a3);
            }
            float apq = (a0 + a1) + (a2 + a3);
            if (apq * apq > 1e-14f * nrm * npart) {
                float tau = (npart - nrm) * 0.5f / apq;
                float tt = copysignf(1.f / (fabsf(tau) + sqrtf(fmaf(tau, tau, 1.f))), tau);
                float cc = rsqrtf(fmaf(tt, tt, 1.f));
                float ss = tt * cc;
                nrm = cc * cc * nrm - 2.f * cc * ss * apq + ss * ss * npart;
#pragma unroll
                for (int k = 0; k < 32; ++k) col[k] = fmaf(cc, col[k], -ss * t[k]);
            }
        }
    }
}

// z = (S * X * S) column c.  Xh: row-major [32][32] in LDS. Sl: row-major in LDS.
__device__ __forceinline__ void sxs_col(const float* Xh, const float* Sl,
                                        int c, float (&z)[32]) {
    float sreg[32];
#pragma unroll
    for (int k = 0; k < 32; ++k) sreg[k] = Sl[k * 32 + c];
    float u[32];
#pragma unroll
    for (int i = 0; i < 32; ++i) {
        float a0 = 0, a1 = 0, a2 = 0, a3 = 0;
#pragma unroll
        for (int k = 0; k < 32; k += 4) {
            const float4 xr = *reinterpret_cast<const float4*>(&Xh[i * 32 + k]);
            a0 = fmaf(xr.x, sreg[k], a0);
            a1 = fmaf(xr.y, sreg[k + 1], a1);
            a2 = fmaf(xr.z, sreg[k + 2], a2);
            a3 = fmaf(xr.w, sreg[k + 3], a3);
        }
        u[i] = (a0 + a1) + (a2 + a3);
    }
#pragma unroll
    for (int i = 0; i < 32; ++i) {
        float a0 = 0, a1 = 0, a2 = 0, a3 = 0;
#pragma unroll
        for (int k = 0; k < 32; k += 4) {
            const float4 sr = *reinterpret_cast<const float4*>(&Sl[i * 32 + k]);
            a0 = fmaf(sr.x, u[k], a0);
            a1 = fmaf(sr.y, u[k + 1], a1);
            a2 = fmaf(sr.z, u[k + 2], a2);
            a3 = fmaf(sr.w, u[k + 3], a3);
        }
        z[i] = (a0 + a1) + (a2 + a3);
    }
}

// Stage this lane's column into Gt row c; coefficient folded into the row padding.
__device__ __forceinline__ void stage_gt(float* Gth, int c, const float (&col)[32], float wtv) {
#pragma unroll
    for (int k = 0; k < 32; k += 4)
        *reinterpret_cast<float4*>(&Gth[c * GT_LD + k]) =
            make_float4(col[k], col[k + 1], col[k + 2], col[k + 3]);
    Gth[c * GT_LD + 32] = wtv;
}

// acc[i] += sum_j wt_j * Gt[j][c] * Gt[j][i]
__device__ __forceinline__ void recon_accum(const float* Gth, int c, float (&acc)[32]) {
    for (int j = 0; j < 32; ++j) {
        float coef = Gth[j * GT_LD + 32] * Gth[j * GT_LD + c];
#pragma unroll
        for (int k = 0; k < 32; k += 4) {
            const float4 g = *reinterpret_cast<const float4*>(&Gth[j * GT_LD + k]);
            acc[k] = fmaf(coef, g.x, acc[k]);
            acc[k + 1] = fmaf(coef, g.y, acc[k + 1]);
            acc[k + 2] = fmaf(coef, g.z, acc[k + 2]);
            acc[k + 3] = fmaf(coef, g.w, acc[k + 3]);
        }
    }
}

__device__ __forceinline__ float half_reduce(float v) {
    v += __shfl_xor(v, 1); v += __shfl_xor(v, 2); v += __shfl_xor(v, 4);
    v += __shfl_xor(v, 8); v += __shfl_xor(v, 16);
    return v;
}

// ---------------- partial/final reductions over 1024-elem matrices ----------------

__global__ __launch_bounds__(256) void k_mean_partial(const float* __restrict__ x,
                                                      float* __restrict__ part) {
    int g = blockIdx.x, tid = threadIdx.x;
    const float* base = x + (size_t)g * 64 * MELEM;
    float a0 = 0, a1 = 0, a2 = 0, a3 = 0;
    for (int b = 0; b < 64; ++b) {
        const float* m = base + b * MELEM;
        a0 += m[tid]; a1 += m[tid + 256]; a2 += m[tid + 512]; a3 += m[tid + 768];
    }
    float* o = part + (size_t)g * MELEM;
    o[tid] = a0; o[tid + 256] = a1; o[tid + 512] = a2; o[tid + 768] = a3;
}

// dst[e] = scale * sum_g src[g*1024+e], e = global thread id (grid 4 x 256).
__global__ __launch_bounds__(256) void k_reduce_small(const float* __restrict__ src,
                                                      float* __restrict__ dst,
                                                      int G, float scale) {
    int e = blockIdx.x * 256 + threadIdx.x;
    float acc = 0.f;
    for (int g = 0; g < G; ++g) acc += src[(size_t)g * MELEM + e];
    dst[e] = acc * scale;
}

// ---------------- prep0: eigh(M0) -> m_s0, m_is0 ----------------

__global__ __launch_bounds__(64) void k_prep0(float* __restrict__ ws) {
    __shared__ alignas(16) float stage[STG_F];
    const int lane = threadIdx.x, h = lane >> 5, c = lane & 31;
    float col[32];
#pragma unroll
    for (int i = 0; i < 32; ++i) col[i] = ws[WS_M0 + i * 32 + c];
    float nrm = colnorm(col);
    onesided_sweeps(col, nrm, NSWEEP_PREP);
    nrm = colnorm(col);
    float* Gth = &stage[h * GT_H];
    float lnn = logf(nrm);
    stage_gt(Gth, c, col, expf(-0.75f * lnn));        // lam^0.5 / lam^2
    float acc[32];
#pragma unroll
    for (int i = 0; i < 32; ++i) acc[i] = 0.f;
    recon_accum(Gth, c, acc);
    if (h == 0) {
#pragma unroll
        for (int i = 0; i < 32; ++i) ws[WS_MS0 + i * 32 + c] = acc[i];
    }
    Gth[c * GT_LD + 32] = expf(-1.25f * lnn);         // lam^-0.5 / lam^2
#pragma unroll
    for (int i = 0; i < 32; ++i) acc[i] = 0.f;
    recon_accum(Gth, c, acc);
    if (h == 0) {
#pragma unroll
        for (int i = 0; i < 32; ++i) ws[WS_MIS0 + i * 32 + c] = acc[i];
    }
}

// ---------------- pass B: per-matrix L = logm(m_is0 x m_is0) -> Lout ----------------

__global__ __launch_bounds__(256, 4) void k_pass_logm(const float* __restrict__ x,
                                                      const float* __restrict__ ws,
                                                      float* __restrict__ Lout) {
    __shared__ alignas(16) float Sl[1024];
    __shared__ alignas(16) float stage[4][STG_F];
    const int tid = threadIdx.x;
    const int wid = tid >> 6, lane = tid & 63, h = lane >> 5, c = lane & 31;
    for (int e = tid; e < 1024; e += 256) Sl[e] = ws[WS_MIS0 + e];
    __syncthreads();
    float* Xw = &stage[wid][0];
    const float* Xh = Xw + h * 1024;
    float* Gth = &stage[wid][h * GT_H];
    const int gw = blockIdx.x * 4 + wid;
    for (int mm = 0; mm < MPW; ++mm) {
        const size_t pairBase = ((size_t)(gw * MPW + mm)) * 2048;
        const float4* gx = reinterpret_cast<const float4*>(x + pairBase);
        float4* X4 = reinterpret_cast<float4*>(Xw);
#pragma unroll
        for (int ch = 0; ch < 8; ++ch) X4[ch * 64 + lane] = gx[ch * 64 + lane];
        float col[32];
        sxs_col(Xh, Sl, c, col);
        float nrm = colnorm(col);
        onesided_sweeps(col, nrm, NSWEEP_BATCH);
        nrm = colnorm(col);
        stage_gt(Gth, c, col, 0.5f * logf(nrm) / nrm);  // log(lam)/lam^2
        float acc[32];
#pragma unroll
        for (int i = 0; i < 32; ++i) acc[i] = 0.f;
        recon_accum(Gth, c, acc);
#pragma unroll
        for (int i = 0; i < 32; ++i) Lout[pairBase + h * 1024 + i * 32 + c] = acc[i];
    }
}

// ---------------- prep1: mean1 = m_s0 expm(t) m_s0 ; m_is1 ----------------

__global__ __launch_bounds__(64) void k_prep1(float* __restrict__ ws) {
    __shared__ alignas(16) float Sl[1024];
    __shared__ alignas(16) float stage[STG_F];
    const int lane = threadIdx.x, h = lane >> 5, c = lane & 31;
    float* Xw = &stage[0];
    const float* Xh = Xw + h * 1024;
    float* Gth = &stage[h * GT_H];

    // t symmetric indefinite: shift by alpha*I so it's SPD
    float col[32];
#pragma unroll
    for (int i = 0; i < 32; ++i) col[i] = ws[WS_T + i * 32 + c];
    float nrm = colnorm(col);
    float fro2 = half_reduce(nrm);
    float alpha = sqrtf(fro2) + 1.0f;
#pragma unroll
    for (int i = 0; i < 32; ++i) col[i] += (i == c) ? alpha : 0.f;
    nrm = colnorm(col);
    onesided_sweeps(col, nrm, NSWEEP_PREP);
    nrm = colnorm(col);
    float nu = sqrtf(nrm);                            // eig of t + alpha I
    stage_gt(Gth, c, col, expf(nu - alpha) / nrm);
    float acc[32];
#pragma unroll
    for (int i = 0; i < 32; ++i) acc[i] = 0.f;
    recon_accum(Gth, c, acc);                         // acc = expm(t) col c
#pragma unroll
    for (int i = 0; i < 32; ++i) Xw[h * 1024 + i * 32 + c] = acc[i];
    for (int e = lane; e < 1024; e += 64) Sl[e] = ws[WS_MS0 + e];
    __syncthreads();
    sxs_col(Xh, Sl, c, col);                          // mean1 = m_s0 E m_s0
    nrm = colnorm(col);
    onesided_sweeps(col, nrm, NSWEEP_PREP);
    nrm = colnorm(col);
    stage_gt(Gth, c, col, expf(-1.25f * logf(nrm)));
#pragma unroll
    for (int i = 0; i < 32; ++i) acc[i] = 0.f;
    recon_accum(Gth, c, acc);
    if (h == 0) {
#pragma unroll
        for (int i = 0; i < 32; ++i) ws[WS_MIS1 + i * 32 + c] = acc[i];
    }
}

// ---------------- pass C: Z = m_is1 x m_is1; eigh; G -> d_out; d2 partials ----------------

__global__ __launch_bounds__(256, 4) void k_pass_dist(const float* __restrict__ x,
                                                      float* __restrict__ ws,
                                                      float* __restrict__ outG) {
    __shared__ alignas(16) float Sl[1024];
    __shared__ alignas(16) float stageX[4][2048];
    const int tid = threadIdx.x;
    const int wid = tid >> 6, lane = tid & 63, h = lane >> 5, c = lane & 31;
    for (int e = tid; e < 1024; e += 256) Sl[e] = ws[WS_MIS1 + e];
    __syncthreads();
    float* Xw = &stageX[wid][0];
    const float* Xh = Xw + h * 1024;
    const int gw = blockIdx.x * 4 + wid;
    float d2acc = 0.f;
    for (int mm = 0; mm < MPW; ++mm) {
        const size_t pairBase = ((size_t)(gw * MPW + mm)) * 2048;
        const float4* gx = reinterpret_cast<const float4*>(x + pairBase);
        float4* X4 = reinterpret_cast<float4*>(Xw);
#pragma unroll
        for (int ch = 0; ch < 8; ++ch) X4[ch * 64 + lane] = gx[ch * 64 + lane];
        float col[32];
        sxs_col(Xh, Sl, c, col);
        float nrm = colnorm(col);
        onesided_sweeps(col, nrm, NSWEEP_BATCH);
        nrm = colnorm(col);
#pragma unroll
        for (int i = 0; i < 32; ++i) outG[pairBase + h * 1024 + i * 32 + c] = col[i];
        float lg = 0.5f * logf(nrm);
        float l2 = lg * lg;
#pragma unroll
        for (int m = 1; m <= 32; m <<= 1) l2 += __shfl_xor(l2, m);
        d2acc += l2;
    }
    if (lane == 0) ws[WS_D2 + gw] = d2acc;
}

__global__ __launch_bounds__(256) void k_finish_p(float* __restrict__ ws,
                                                  const float* __restrict__ scale) {
    __shared__ float sm[256];
    int tid = threadIdx.x;
    float acc = 0.f;
    for (int g = tid; g < NW; g += 256) acc += ws[WS_D2 + g];
    sm[tid] = acc;
    __syncthreads();
    for (int off = 128; off > 0; off >>= 1) {
        if (tid < off) sm[tid] += sm[tid + off];
        __syncthreads();
    }
    if (tid == 0) {
        float sd = sqrtf(sm[0] / (float)BATCH);
        ws[WS_P] = scale[0] / (sd + EPSF);
    }
}

// ---------------- pass D: out = G diag(nrm^(p/2-1)) G^T ----------------

__global__ __launch_bounds__(256, 4) void k_out_recon(float* __restrict__ outG,
                                                      const float* __restrict__ ws) {
    __shared__ alignas(16) float stage[4][STG_F];
    const int tid = threadIdx.x;
    const int wid = tid >> 6, lane = tid & 63, h = lane >> 5, c = lane & 31;
    float* Gth = &stage[wid][h * GT_H];
    const float p = ws[WS_P];
    const float ex = 0.5f * p - 1.0f;                 // lam^p / lam^2
    const int gw = blockIdx.x * 4 + wid;
    for (int mm = 0; mm < MPW; ++mm) {
        const size_t pairBase = ((size_t)(gw * MPW + mm)) * 2048;
        float col[32];
#pragma unroll
        for (int i = 0; i < 32; ++i) col[i] = outG[pairBase + h * 1024 + i * 32 + c];
        float nrm = colnorm(col);
        stage_gt(Gth, c, col, expf(ex * logf(nrm)));
        float acc[32];
#pragma unroll
        for (int i = 0; i < 32; ++i) acc[i] = 0.f;
        recon_accum(Gth, c, acc);
#pragma unroll
        for (int i = 0; i < 32; ++i) outG[pairBase + h * 1024 + i * 32 + c] = acc[i];
    }
}

// ---------------- launch ----------------

extern "C" void kernel_launch(void* const* d_in, const int* in_sizes, int n_in,
                              void* d_out, int out_size, void* d_ws, size_t ws_size,
                              hipStream_t stream) {
    const float* x = (const float*)d_in[0];
    const float* scale = (const float*)d_in[1];
    float* out = (float*)d_out;
    float* ws = (float*)d_ws;
    const bool big = ws_size >= WS_NEED_BIG;

    // arithmetic mean -> M0
    k_mean_partial<<<G0, 256, 0, stream>>>(x, out);
    k_reduce_small<<<4, 256, 0, stream>>>(out, ws + WS_M0, G0, 1.0f / (float)BATCH);
    k_prep0<<<1, 64, 0, stream>>>(ws);
    // Karcher tangent mean: per-matrix logm into d_out, then reduce
    k_pass_logm<<<NBLK, 256, 0, stream>>>(x, ws, out);
    if (big) {
        k_mean_partial<<<G0, 256, 0, stream>>>(out, ws + WS_PART2);
        k_reduce_small<<<4, 256, 0, stream>>>(ws + WS_PART2, ws + WS_T, G0, 1.0f / (float)BATCH);
    } else {
        k_reduce_small<<<4, 256, 0, stream>>>(out, ws + WS_T, BATCH, 1.0f / (float)BATCH);
    }
    k_prep1<<<1, 64, 0, stream>>>(ws);
    // distance pass (+ store G)
    k_pass_dist<<<NBLK, 256, 0, stream>>>(x, ws, out);
    k_finish_p<<<1, 256, 0, stream>>>(ws, scale);
    // output
    k_out_recon<<<NBLK, 256, 0, stream>>>(out, ws);
}

// Round 5
// 4348.197 us; speedup vs baseline: 1.0254x; 1.0254x over previous
//
#include <hip/hip_runtime.h>
#include <math.h>

#define BATCH 32768
#define MELEM 1024
#define NSWEEP_BATCH 7
#define NSWEEP_PREP 8
#define MPW 4                    // matrix-PAIRS per wave
#define WPB 8                    // waves per block
#define NTHREADS (WPB * 64)      // 512
#define NW (BATCH / (2 * MPW))   // 4096 waves in batch passes
#define NBLK (NW / WPB)          // 512 blocks (8 waves/block, 2 blocks/CU)
#define G0 512                   // blocks for partial-mean passes
#define EPSF 1e-5f

// ws layout (float offsets)
#define WS_M0    0
#define WS_MS0   1024
#define WS_MIS0  2048
#define WS_T     3072
#define WS_MIS1  4096
#define WS_P     5120
#define WS_D2    5184            // NW floats
#define WS_PART2 16384           // 512*1024 floats (t-reduction partials)
#define WS_NEED_BIG ((WS_PART2 + G0 * MELEM) * sizeof(float))

// per-wave LDS stage: union of X[2][1024] and Gt[2][32][36] (wt folded at col 32)
#define GT_LD 36
#define GT_H 1152                // 32*36
#define STG_F 2304               // floats per wave

#define HEAVY_ATTRS __attribute__((amdgpu_flat_work_group_size(NTHREADS, NTHREADS), \
                                   amdgpu_waves_per_eu(4, 4)))

// ---------------- register helpers ----------------

__device__ __forceinline__ float colnorm(const float (&col)[32]) {
    float a0 = 0, a1 = 0, a2 = 0, a3 = 0;
#pragma unroll
    for (int k = 0; k < 32; k += 4) {
        a0 = fmaf(col[k], col[k], a0);
        a1 = fmaf(col[k + 1], col[k + 1], a1);
        a2 = fmaf(col[k + 2], col[k + 2], a2);
        a3 = fmaf(col[k + 3], col[k + 3], a3);
    }
    return (a0 + a1) + (a2 + a3);
}

// One-sided (Hestenes) Jacobi, fixed sweep count (validated rounds 2/4).
// Lane (h,c) owns column c. XOR ordering: round m pairs c with c^m.
__device__ __forceinline__ void onesided_sweeps(float (&col)[32], float &nrm, int nsweeps) {
    for (int sw = 0; sw < nsweeps; ++sw) {
        for (int m = 1; m < 32; ++m) {
            float t[32];
            float npart = __shfl_xor(nrm, m);
            float a0 = 0, a1 = 0, a2 = 0, a3 = 0;
#pragma unroll
            for (int k = 0; k < 32; k += 4) {
                t[k] = __shfl_xor(col[k], m);
                t[k + 1] = __shfl_xor(col[k + 1], m);
                t[k + 2] = __shfl_xor(col[k + 2], m);
                t[k + 3] = __shfl_xor(col[k + 3], m);
                a0 = fmaf(col[k], t[k], a0);
                a1 = fmaf(col[k + 1], t[k + 1], a1);
                a2 = fmaf(col[k + 2], t[k + 2], a2);
                a3 = fmaf(col[k + 3], t[k + 3], a3);
            }
            float apq = (a0 + a1) + (a2 + a3);
            if (apq * apq > 1e-14f * nrm * npart) {
                float tau = (npart - nrm) * 0.5f / apq;
                float tt = copysignf(1.f / (fabsf(tau) + sqrtf(fmaf(tau, tau, 1.f))), tau);
                float cc = rsqrtf(fmaf(tt, tt, 1.f));
                float ss = tt * cc;
                nrm = cc * cc * nrm - 2.f * cc * ss * apq + ss * ss * npart;
#pragma unroll
                for (int k = 0; k < 32; ++k) col[k] = fmaf(cc, col[k], -ss * t[k]);
            }
        }
    }
}

// z = (S * X * S) column c.  Xh: row-major [32][32] in LDS. Sl: row-major in LDS.
__device__ __forceinline__ void sxs_col(const float* Xh, const float* Sl,
                                        int c, float (&z)[32]) {
    float sreg[32];
#pragma unroll
    for (int k = 0; k < 32; ++k) sreg[k] = Sl[k * 32 + c];
    float u[32];
#pragma unroll
    for (int i = 0; i < 32; ++i) {
        float a0 = 0, a1 = 0, a2 = 0, a3 = 0;
#pragma unroll
        for (int k = 0; k < 32; k += 4) {
            const float4 xr = *reinterpret_cast<const float4*>(&Xh[i * 32 + k]);
            a0 = fmaf(xr.x, sreg[k], a0);
            a1 = fmaf(xr.y, sreg[k + 1], a1);
            a2 = fmaf(xr.z, sreg[k + 2], a2);
            a3 = fmaf(xr.w, sreg[k + 3], a3);
        }
        u[i] = (a0 + a1) + (a2 + a3);
    }
#pragma unroll
    for (int i = 0; i < 32; ++i) {
        float a0 = 0, a1 = 0, a2 = 0, a3 = 0;
#pragma unroll
        for (int k = 0; k < 32; k += 4) {
            const float4 sr = *reinterpret_cast<const float4*>(&Sl[i * 32 + k]);
            a0 = fmaf(sr.x, u[k], a0);
            a1 = fmaf(sr.y, u[k + 1], a1);
            a2 = fmaf(sr.z, u[k + 2], a2);
            a3 = fmaf(sr.w, u[k + 3], a3);
        }
        z[i] = (a0 + a1) + (a2 + a3);
    }
}

// Stage this lane's column into Gt row c; coefficient folded into the row padding.
__device__ __forceinline__ void stage_gt(float* Gth, int c, const float (&col)[32], float wtv) {
#pragma unroll
    for (int k = 0; k < 32; k += 4)
        *reinterpret_cast<float4*>(&Gth[c * GT_LD + k]) =
            make_float4(col[k], col[k + 1], col[k + 2], col[k + 3]);
    Gth[c * GT_LD + 32] = wtv;
}

// acc[i] += sum_j wt_j * Gt[j][c] * Gt[j][i]
__device__ __forceinline__ void recon_accum(const float* Gth, int c, float (&acc)[32]) {
    for (int j = 0; j < 32; ++j) {
        float coef = Gth[j * GT_LD + 32] * Gth[j * GT_LD + c];
#pragma unroll
        for (int k = 0; k < 32; k += 4) {
            const float4 g = *reinterpret_cast<const float4*>(&Gth[j * GT_LD + k]);
            acc[k] = fmaf(coef, g.x, acc[k]);
            acc[k + 1] = fmaf(coef, g.y, acc[k + 1]);
            acc[k + 2] = fmaf(coef, g.z, acc[k + 2]);
            acc[k + 3] = fmaf(coef, g.w, acc[k + 3]);
        }
    }
}

__device__ __forceinline__ float half_reduce(float v) {
    v += __shfl_xor(v, 1); v += __shfl_xor(v, 2); v += __shfl_xor(v, 4);
    v += __shfl_xor(v, 8); v += __shfl_xor(v, 16);
    return v;
}

// ---------------- partial/final reductions over 1024-elem matrices ----------------

__global__ __launch_bounds__(256) void k_mean_partial(const float* __restrict__ x,
                                                      float* __restrict__ part) {
    int g = blockIdx.x, tid = threadIdx.x;
    const float* base = x + (size_t)g * 64 * MELEM;
    float a0 = 0, a1 = 0, a2 = 0, a3 = 0;
    for (int b = 0; b < 64; ++b) {
        const float* m = base + b * MELEM;
        a0 += m[tid]; a1 += m[tid + 256]; a2 += m[tid + 512]; a3 += m[tid + 768];
    }
    float* o = part + (size_t)g * MELEM;
    o[tid] = a0; o[tid + 256] = a1; o[tid + 512] = a2; o[tid + 768] = a3;
}

// dst[e] = scale * sum_g src[g*1024+e], e = global thread id (grid 4 x 256).
__global__ __launch_bounds__(256) void k_reduce_small(const float* __restrict__ src,
                                                      float* __restrict__ dst,
                                                      int G, float scale) {
    int e = blockIdx.x * 256 + threadIdx.x;
    float acc = 0.f;
    for (int g = 0; g < G; ++g) acc += src[(size_t)g * MELEM + e];
    dst[e] = acc * scale;
}

// ---------------- prep0: eigh(M0) -> m_s0, m_is0 ----------------

__global__ __launch_bounds__(64) void k_prep0(float* __restrict__ ws) {
    __shared__ alignas(16) float stage[STG_F];
    const int lane = threadIdx.x, h = lane >> 5, c = lane & 31;
    float col[32];
#pragma unroll
    for (int i = 0; i < 32; ++i) col[i] = ws[WS_M0 + i * 32 + c];
    float nrm = colnorm(col);
    onesided_sweeps(col, nrm, NSWEEP_PREP);
    nrm = colnorm(col);
    float* Gth = &stage[h * GT_H];
    float lnn = logf(nrm);
    stage_gt(Gth, c, col, expf(-0.75f * lnn));        // lam^0.5 / lam^2
    float acc[32];
#pragma unroll
    for (int i = 0; i < 32; ++i) acc[i] = 0.f;
    recon_accum(Gth, c, acc);
    if (h == 0) {
#pragma unroll
        for (int i = 0; i < 32; ++i) ws[WS_MS0 + i * 32 + c] = acc[i];
    }
    Gth[c * GT_LD + 32] = expf(-1.25f * lnn);         // lam^-0.5 / lam^2
#pragma unroll
    for (int i = 0; i < 32; ++i) acc[i] = 0.f;
    recon_accum(Gth, c, acc);
    if (h == 0) {
#pragma unroll
        for (int i = 0; i < 32; ++i) ws[WS_MIS0 + i * 32 + c] = acc[i];
    }
}

// ---------------- pass B: per-matrix L = logm(m_is0 x m_is0) -> Lout ----------------

__global__ HEAVY_ATTRS void k_pass_logm(const float* __restrict__ x,
                                        const float* __restrict__ ws,
                                        float* __restrict__ Lout) {
    __shared__ alignas(16) float Sl[1024];
    __shared__ alignas(16) float stage[WPB][STG_F];
    const int tid = threadIdx.x;
    const int wid = tid >> 6, lane = tid & 63, h = lane >> 5, c = lane & 31;
    for (int e = tid; e < 1024; e += NTHREADS) Sl[e] = ws[WS_MIS0 + e];
    __syncthreads();
    float* Xw = &stage[wid][0];
    const float* Xh = Xw + h * 1024;
    float* Gth = &stage[wid][h * GT_H];
    const int gw = blockIdx.x * WPB + wid;
    for (int mm = 0; mm < MPW; ++mm) {
        const size_t pairBase = ((size_t)(gw * MPW + mm)) * 2048;
        const float4* gx = reinterpret_cast<const float4*>(x + pairBase);
        float4* X4 = reinterpret_cast<float4*>(Xw);
#pragma unroll
        for (int ch = 0; ch < 8; ++ch) X4[ch * 64 + lane] = gx[ch * 64 + lane];
        float col[32];
        sxs_col(Xh, Sl, c, col);
        float nrm = colnorm(col);
        onesided_sweeps(col, nrm, NSWEEP_BATCH);
        nrm = colnorm(col);
        stage_gt(Gth, c, col, 0.5f * logf(nrm) / nrm);  // log(lam)/lam^2
        float acc[32];
#pragma unroll
        for (int i = 0; i < 32; ++i) acc[i] = 0.f;
        recon_accum(Gth, c, acc);
#pragma unroll
        for (int i = 0; i < 32; ++i) Lout[pairBase + h * 1024 + i * 32 + c] = acc[i];
    }
}

// ---------------- prep1: mean1 = m_s0 expm(t) m_s0 ; m_is1 ----------------

__global__ __launch_bounds__(64) void k_prep1(float* __restrict__ ws) {
    __shared__ alignas(16) float Sl[1024];
    __shared__ alignas(16) float stage[STG_F];
    const int lane = threadIdx.x, h = lane >> 5, c = lane & 31;
    float* Xw = &stage[0];
    const float* Xh = Xw + h * 1024;
    float* Gth = &stage[h * GT_H];

    // t symmetric indefinite: shift by alpha*I so it's SPD
    float col[32];
#pragma unroll
    for (int i = 0; i < 32; ++i) col[i] = ws[WS_T + i * 32 + c];
    float nrm = colnorm(col);
    float fro2 = half_reduce(nrm);
    float alpha = sqrtf(fro2) + 1.0f;
#pragma unroll
    for (int i = 0; i < 32; ++i) col[i] += (i == c) ? alpha : 0.f;
    nrm = colnorm(col);
    onesided_sweeps(col, nrm, NSWEEP_PREP);
    nrm = colnorm(col);
    float nu = sqrtf(nrm);                            // eig of t + alpha I
    stage_gt(Gth, c, col, expf(nu - alpha) / nrm);
    float acc[32];
#pragma unroll
    for (int i = 0; i < 32; ++i) acc[i] = 0.f;
    recon_accum(Gth, c, acc);                         // acc = expm(t) col c
#pragma unroll
    for (int i = 0; i < 32; ++i) Xw[h * 1024 + i * 32 + c] = acc[i];
    for (int e = lane; e < 1024; e += 64) Sl[e] = ws[WS_MS0 + e];
    __syncthreads();
    sxs_col(Xh, Sl, c, col);                          // mean1 = m_s0 E m_s0
    nrm = colnorm(col);
    onesided_sweeps(col, nrm, NSWEEP_PREP);
    nrm = colnorm(col);
    stage_gt(Gth, c, col, expf(-1.25f * logf(nrm)));
#pragma unroll
    for (int i = 0; i < 32; ++i) acc[i] = 0.f;
    recon_accum(Gth, c, acc);
    if (h == 0) {
#pragma unroll
        for (int i = 0; i < 32; ++i) ws[WS_MIS1 + i * 32 + c] = acc[i];
    }
}

// ---------------- pass C: Z = m_is1 x m_is1; eigh; G -> d_out; d2 partials ----------------

__global__ HEAVY_ATTRS void k_pass_dist(const float* __restrict__ x,
                                        float* __restrict__ ws,
                                        float* __restrict__ outG) {
    __shared__ alignas(16) float Sl[1024];
    __shared__ alignas(16) float stageX[WPB][2048];
    const int tid = threadIdx.x;
    const int wid = tid >> 6, lane = tid & 63, h = lane >> 5, c = lane & 31;
    for (int e = tid; e < 1024; e += NTHREADS) Sl[e] = ws[WS_MIS1 + e];
    __syncthreads();
    float* Xw = &stageX[wid][0];
    const float* Xh = Xw + h * 1024;
    const int gw = blockIdx.x * WPB + wid;
    float d2acc = 0.f;
    for (int mm = 0; mm < MPW; ++mm) {
        const size_t pairBase = ((size_t)(gw * MPW + mm)) * 2048;
        const float4* gx = reinterpret_cast<const float4*>(x + pairBase);
        float4* X4 = reinterpret_cast<float4*>(Xw);
#pragma unroll
        for (int ch = 0; ch < 8; ++ch) X4[ch * 64 + lane] = gx[ch * 64 + lane];
        float col[32];
        sxs_col(Xh, Sl, c, col);
        float nrm = colnorm(col);
        onesided_sweeps(col, nrm, NSWEEP_BATCH);
        nrm = colnorm(col);
#pragma unroll
        for (int i = 0; i < 32; ++i) outG[pairBase + h * 1024 + i * 32 + c] = col[i];
        float lg = 0.5f * logf(nrm);
        float l2 = lg * lg;
#pragma unroll
        for (int m = 1; m <= 32; m <<= 1) l2 += __shfl_xor(l2, m);
        d2acc += l2;
    }
    if (lane == 0) ws[WS_D2 + gw] = d2acc;
}

__global__ __launch_bounds__(256) void k_finish_p(float* __restrict__ ws,
                                                  const float* __restrict__ scale) {
    __shared__ float sm[256];
    int tid = threadIdx.x;
    float acc = 0.f;
    for (int g = tid; g < NW; g += 256) acc += ws[WS_D2 + g];
    sm[tid] = acc;
    __syncthreads();
    for (int off = 128; off > 0; off >>= 1) {
        if (tid < off) sm[tid] += sm[tid + off];
        __syncthreads();
    }
    if (tid == 0) {
        float sd = sqrtf(sm[0] / (float)BATCH);
        ws[WS_P] = scale[0] / (sd + EPSF);
    }
}

// ---------------- pass D: out = G diag(nrm^(p/2-1)) G^T ----------------

__global__ HEAVY_ATTRS void k_out_recon(float* __restrict__ outG,
                                        const float* __restrict__ ws) {
    __shared__ alignas(16) float stage[WPB][STG_F];
    const int tid = threadIdx.x;
    const int wid = tid >> 6, lane = tid & 63, h = lane >> 5, c = lane & 31;
    float* Gth = &stage[wid][h * GT_H];
    const float p = ws[WS_P];
    const float ex = 0.5f * p - 1.0f;                 // lam^p / lam^2
    const int gw = blockIdx.x * WPB + wid;
    for (int mm = 0; mm < MPW; ++mm) {
        const size_t pairBase = ((size_t)(gw * MPW + mm)) * 2048;
        float col[32];
#pragma unroll
        for (int i = 0; i < 32; ++i) col[i] = outG[pairBase + h * 1024 + i * 32 + c];
        float nrm = colnorm(col);
        stage_gt(Gth, c, col, expf(ex * logf(nrm)));
        float acc[32];
#pragma unroll
        for (int i = 0; i < 32; ++i) acc[i] = 0.f;
        recon_accum(Gth, c, acc);
#pragma unroll
        for (int i = 0; i < 32; ++i) outG[pairBase + h * 1024 + i * 32 + c] = acc[i];
    }
}

// ---------------- launch ----------------

extern "C" void kernel_launch(void* const* d_in, const int* in_sizes, int n_in,
                              void* d_out, int out_size, void* d_ws, size_t ws_size,
                              hipStream_t stream) {
    const float* x = (const float*)d_in[0];
    const float* scale = (const float*)d_in[1];
    float* out = (float*)d_out;
    float* ws = (float*)d_ws;
    const bool big = ws_size >= WS_NEED_BIG;

    // arithmetic mean -> M0
    k_mean_partial<<<G0, 256, 0, stream>>>(x, out);
    k_reduce_small<<<4, 256, 0, stream>>>(out, ws + WS_M0, G0, 1.0f / (float)BATCH);
    k_prep0<<<1, 64, 0, stream>>>(ws);
    // Karcher tangent mean: per-matrix logm into d_out, then reduce
    k_pass_logm<<<NBLK, NTHREADS, 0, stream>>>(x, ws, out);
    if (big) {
        k_mean_partial<<<G0, 256, 0, stream>>>(out, ws + WS_PART2);
        k_reduce_small<<<4, 256, 0, stream>>>(ws + WS_PART2, ws + WS_T, G0, 1.0f / (float)BATCH);
    } else {
        k_reduce_small<<<4, 256, 0, stream>>>(out, ws + WS_T, BATCH, 1.0f / (float)BATCH);
    }
    k_prep1<<<1, 64, 0, stream>>>(ws);
    // distance pass (+ store G)
    k_pass_dist<<<NBLK, NTHREADS, 0, stream>>>(x, ws, out);
    k_finish_p<<<1, 256, 0, stream>>>(ws, scale);
    // output
    k_out_recon<<<NBLK, NTHREADS, 0, stream>>>(out, ws);
}

// Round 6
// 3892.607 us; speedup vs baseline: 1.1454x; 1.1170x over previous
//
#include <hip/hip_runtime.h>
#include <math.h>

#define BATCH 32768
#define MELEM 1024
#define NSWEEP_BATCH 7
#define NSWEEP_PREP 8
#define MPW 4                    // matrix-PAIRS per wave
#define WPB 4                    // waves per block
#define NTHREADS (WPB * 64)      // 256
#define NW (BATCH / (2 * MPW))   // 4096 waves in batch passes
#define NBLK (NW / WPB)          // 1024 blocks
#define G0 512                   // blocks for partial-mean passes
#define EPSF 1e-5f

// ws layout (float offsets)
#define WS_M0    0
#define WS_MS0   1024
#define WS_MIS0  2048
#define WS_T     3072
#define WS_MIS1  4096
#define WS_P     5120
#define WS_D2    5184            // NW floats
#define WS_PART2 16384           // 512*1024 floats (t-reduction partials)
#define WS_NEED_BIG ((WS_PART2 + G0 * MELEM) * sizeof(float))

// per-wave LDS stage: union of X[2][1024] and Gt[2][32][36] (wt folded at col 32)
#define GT_LD 36
#define GT_H 1152                // 32*36
#define STG_F 2304               // floats per wave

// min 2 waves/EU -> register budget 256; allocator empirically grants half
// of budget to arch VGPRs (r2/r4/r5 data) -> ~128 arch VGPRs -> no spill.
#define HEAVY_ATTRS __attribute__((amdgpu_flat_work_group_size(NTHREADS, NTHREADS), \
                                   amdgpu_waves_per_eu(2, 4)))

// ---------------- register helpers ----------------

__device__ __forceinline__ float colnorm(const float (&col)[32]) {
    float a0 = 0, a1 = 0, a2 = 0, a3 = 0;
#pragma unroll
    for (int k = 0; k < 32; k += 4) {
        a0 = fmaf(col[k], col[k], a0);
        a1 = fmaf(col[k + 1], col[k + 1], a1);
        a2 = fmaf(col[k + 2], col[k + 2], a2);
        a3 = fmaf(col[k + 3], col[k + 3], a3);
    }
    return (a0 + a1) + (a2 + a3);
}

// One-sided (Hestenes) Jacobi, fixed sweep count (validated rounds 2/4/5).
// Lane (h,c) owns column c. XOR ordering: round m pairs c with c^m.
__device__ __forceinline__ void onesided_sweeps(float (&col)[32], float &nrm, int nsweeps) {
    for (int sw = 0; sw < nsweeps; ++sw) {
        for (int m = 1; m < 32; ++m) {
            float t[32];
            float npart = __shfl_xor(nrm, m);
            float a0 = 0, a1 = 0, a2 = 0, a3 = 0;
#pragma unroll
            for (int k = 0; k < 32; k += 4) {
                t[k] = __shfl_xor(col[k], m);
                t[k + 1] = __shfl_xor(col[k + 1], m);
                t[k + 2] = __shfl_xor(col[k + 2], m);
                t[k + 3] = __shfl_xor(col[k + 3], m);
                a0 = fmaf(col[k], t[k], a0);
                a1 = fmaf(col[k + 1], t[k + 1], a1);
                a2 = fmaf(col[k + 2], t[k + 2], a2);
                a3 = fmaf(col[k + 3], t[k + 3], a3);
            }
            float apq = (a0 + a1) + (a2 + a3);
            if (apq * apq > 1e-14f * nrm * npart) {
                float tau = (npart - nrm) * 0.5f / apq;
                float tt = copysignf(1.f / (fabsf(tau) + sqrtf(fmaf(tau, tau, 1.f))), tau);
                float cc = rsqrtf(fmaf(tt, tt, 1.f));
                float ss = tt * cc;
                nrm = cc * cc * nrm - 2.f * cc * ss * apq + ss * ss * npart;
#pragma unroll
                for (int k = 0; k < 32; ++k) col[k] = fmaf(cc, col[k], -ss * t[k]);
            }
        }
    }
}

// z = (S * X * S) column c.  Xh: row-major [32][32] in LDS. Sl: row-major in LDS.
__device__ __forceinline__ void sxs_col(const float* Xh, const float* Sl,
                                        int c, float (&z)[32]) {
    float sreg[32];
#pragma unroll
    for (int k = 0; k < 32; ++k) sreg[k] = Sl[k * 32 + c];
    float u[32];
#pragma unroll
    for (int i = 0; i < 32; ++i) {
        float a0 = 0, a1 = 0, a2 = 0, a3 = 0;
#pragma unroll
        for (int k = 0; k < 32; k += 4) {
            const float4 xr = *reinterpret_cast<const float4*>(&Xh[i * 32 + k]);
            a0 = fmaf(xr.x, sreg[k], a0);
            a1 = fmaf(xr.y, sreg[k + 1], a1);
            a2 = fmaf(xr.z, sreg[k + 2], a2);
            a3 = fmaf(xr.w, sreg[k + 3], a3);
        }
        u[i] = (a0 + a1) + (a2 + a3);
    }
#pragma unroll
    for (int i = 0; i < 32; ++i) {
        float a0 = 0, a1 = 0, a2 = 0, a3 = 0;
#pragma unroll
        for (int k = 0; k < 32; k += 4) {
            const float4 sr = *reinterpret_cast<const float4*>(&Sl[i * 32 + k]);
            a0 = fmaf(sr.x, u[k], a0);
            a1 = fmaf(sr.y, u[k + 1], a1);
            a2 = fmaf(sr.z, u[k + 2], a2);
            a3 = fmaf(sr.w, u[k + 3], a3);
        }
        z[i] = (a0 + a1) + (a2 + a3);
    }
}

// Stage this lane's column into Gt row c; coefficient folded into the row padding.
__device__ __forceinline__ void stage_gt(float* Gth, int c, const float (&col)[32], float wtv) {
#pragma unroll
    for (int k = 0; k < 32; k += 4)
        *reinterpret_cast<float4*>(&Gth[c * GT_LD + k]) =
            make_float4(col[k], col[k + 1], col[k + 2], col[k + 3]);
    Gth[c * GT_LD + 32] = wtv;
}

// acc[i] += sum_j wt_j * Gt[j][c] * Gt[j][i]
__device__ __forceinline__ void recon_accum(const float* Gth, int c, float (&acc)[32]) {
    for (int j = 0; j < 32; ++j) {
        float coef = Gth[j * GT_LD + 32] * Gth[j * GT_LD + c];
#pragma unroll
        for (int k = 0; k < 32; k += 4) {
            const float4 g = *reinterpret_cast<const float4*>(&Gth[j * GT_LD + k]);
            acc[k] = fmaf(coef, g.x, acc[k]);
            acc[k + 1] = fmaf(coef, g.y, acc[k + 1]);
            acc[k + 2] = fmaf(coef, g.z, acc[k + 2]);
            acc[k + 3] = fmaf(coef, g.w, acc[k + 3]);
        }
    }
}

__device__ __forceinline__ float half_reduce(float v) {
    v += __shfl_xor(v, 1); v += __shfl_xor(v, 2); v += __shfl_xor(v, 4);
    v += __shfl_xor(v, 8); v += __shfl_xor(v, 16);
    return v;
}

// ---------------- partial/final reductions over 1024-elem matrices ----------------

__global__ __launch_bounds__(256) void k_mean_partial(const float* __restrict__ x,
                                                      float* __restrict__ part) {
    int g = blockIdx.x, tid = threadIdx.x;
    const float* base = x + (size_t)g * 64 * MELEM;
    float a0 = 0, a1 = 0, a2 = 0, a3 = 0;
    for (int b = 0; b < 64; ++b) {
        const float* m = base + b * MELEM;
        a0 += m[tid]; a1 += m[tid + 256]; a2 += m[tid + 512]; a3 += m[tid + 768];
    }
    float* o = part + (size_t)g * MELEM;
    o[tid] = a0; o[tid + 256] = a1; o[tid + 512] = a2; o[tid + 768] = a3;
}

// dst[e] = scale * sum_g src[g*1024+e], e = global thread id (grid 4 x 256).
__global__ __launch_bounds__(256) void k_reduce_small(const float* __restrict__ src,
                                                      float* __restrict__ dst,
                                                      int G, float scale) {
    int e = blockIdx.x * 256 + threadIdx.x;
    float acc = 0.f;
    for (int g = 0; g < G; ++g) acc += src[(size_t)g * MELEM + e];
    dst[e] = acc * scale;
}

// ---------------- prep0: eigh(M0) -> m_s0, m_is0 ----------------

__global__ __launch_bounds__(64) void k_prep0(float* __restrict__ ws) {
    __shared__ alignas(16) float stage[STG_F];
    const int lane = threadIdx.x, h = lane >> 5, c = lane & 31;
    float col[32];
#pragma unroll
    for (int i = 0; i < 32; ++i) col[i] = ws[WS_M0 + i * 32 + c];
    float nrm = colnorm(col);
    onesided_sweeps(col, nrm, NSWEEP_PREP);
    nrm = colnorm(col);
    float* Gth = &stage[h * GT_H];
    float lnn = logf(nrm);
    stage_gt(Gth, c, col, expf(-0.75f * lnn));        // lam^0.5 / lam^2
    float acc[32];
#pragma unroll
    for (int i = 0; i < 32; ++i) acc[i] = 0.f;
    recon_accum(Gth, c, acc);
    if (h == 0) {
#pragma unroll
        for (int i = 0; i < 32; ++i) ws[WS_MS0 + i * 32 + c] = acc[i];
    }
    Gth[c * GT_LD + 32] = expf(-1.25f * lnn);         // lam^-0.5 / lam^2
#pragma unroll
    for (int i = 0; i < 32; ++i) acc[i] = 0.f;
    recon_accum(Gth, c, acc);
    if (h == 0) {
#pragma unroll
        for (int i = 0; i < 32; ++i) ws[WS_MIS0 + i * 32 + c] = acc[i];
    }
}

// ---------------- pass B: per-matrix L = logm(m_is0 x m_is0) -> Lout ----------------

__global__ HEAVY_ATTRS void k_pass_logm(const float* __restrict__ x,
                                        const float* __restrict__ ws,
                                        float* __restrict__ Lout) {
    __shared__ alignas(16) float Sl[1024];
    __shared__ alignas(16) float stage[WPB][STG_F];
    const int tid = threadIdx.x;
    const int wid = tid >> 6, lane = tid & 63, h = lane >> 5, c = lane & 31;
    for (int e = tid; e < 1024; e += NTHREADS) Sl[e] = ws[WS_MIS0 + e];
    __syncthreads();
    float* Xw = &stage[wid][0];
    const float* Xh = Xw + h * 1024;
    float* Gth = &stage[wid][h * GT_H];
    const int gw = blockIdx.x * WPB + wid;
    for (int mm = 0; mm < MPW; ++mm) {
        const size_t pairBase = ((size_t)(gw * MPW + mm)) * 2048;
        const float4* gx = reinterpret_cast<const float4*>(x + pairBase);
        float4* X4 = reinterpret_cast<float4*>(Xw);
#pragma unroll
        for (int ch = 0; ch < 8; ++ch) X4[ch * 64 + lane] = gx[ch * 64 + lane];
        float col[32];
        sxs_col(Xh, Sl, c, col);
        float nrm = colnorm(col);
        onesided_sweeps(col, nrm, NSWEEP_BATCH);
        nrm = colnorm(col);
        stage_gt(Gth, c, col, 0.5f * logf(nrm) / nrm);  // log(lam)/lam^2
        float acc[32];
#pragma unroll
        for (int i = 0; i < 32; ++i) acc[i] = 0.f;
        recon_accum(Gth, c, acc);
#pragma unroll
        for (int i = 0; i < 32; ++i) Lout[pairBase + h * 1024 + i * 32 + c] = acc[i];
    }
}

// ---------------- prep1: mean1 = m_s0 expm(t) m_s0 ; m_is1 ----------------

__global__ __launch_bounds__(64) void k_prep1(float* __restrict__ ws) {
    __shared__ alignas(16) float Sl[1024];
    __shared__ alignas(16) float stage[STG_F];
    const int lane = threadIdx.x, h = lane >> 5, c = lane & 31;
    float* Xw = &stage[0];
    const float* Xh = Xw + h * 1024;
    float* Gth = &stage[h * GT_H];

    // t symmetric indefinite: shift by alpha*I so it's SPD
    float col[32];
#pragma unroll
    for (int i = 0; i < 32; ++i) col[i] = ws[WS_T + i * 32 + c];
    float nrm = colnorm(col);
    float fro2 = half_reduce(nrm);
    float alpha = sqrtf(fro2) + 1.0f;
#pragma unroll
    for (int i = 0; i < 32; ++i) col[i] += (i == c) ? alpha : 0.f;
    nrm = colnorm(col);
    onesided_sweeps(col, nrm, NSWEEP_PREP);
    nrm = colnorm(col);
    float nu = sqrtf(nrm);                            // eig of t + alpha I
    stage_gt(Gth, c, col, expf(nu - alpha) / nrm);
    float acc[32];
#pragma unroll
    for (int i = 0; i < 32; ++i) acc[i] = 0.f;
    recon_accum(Gth, c, acc);                         // acc = expm(t) col c
#pragma unroll
    for (int i = 0; i < 32; ++i) Xw[h * 1024 + i * 32 + c] = acc[i];
    for (int e = lane; e < 1024; e += 64) Sl[e] = ws[WS_MS0 + e];
    __syncthreads();
    sxs_col(Xh, Sl, c, col);                          // mean1 = m_s0 E m_s0
    nrm = colnorm(col);
    onesided_sweeps(col, nrm, NSWEEP_PREP);
    nrm = colnorm(col);
    stage_gt(Gth, c, col, expf(-1.25f * logf(nrm)));
#pragma unroll
    for (int i = 0; i < 32; ++i) acc[i] = 0.f;
    recon_accum(Gth, c, acc);
    if (h == 0) {
#pragma unroll
        for (int i = 0; i < 32; ++i) ws[WS_MIS1 + i * 32 + c] = acc[i];
    }
}

// ---------------- pass C: Z = m_is1 x m_is1; eigh; G -> d_out; d2 partials ----------------

__global__ HEAVY_ATTRS void k_pass_dist(const float* __restrict__ x,
                                        float* __restrict__ ws,
                                        float* __restrict__ outG) {
    __shared__ alignas(16) float Sl[1024];
    __shared__ alignas(16) float stageX[WPB][2048];
    const int tid = threadIdx.x;
    const int wid = tid >> 6, lane = tid & 63, h = lane >> 5, c = lane & 31;
    for (int e = tid; e < 1024; e += NTHREADS) Sl[e] = ws[WS_MIS1 + e];
    __syncthreads();
    float* Xw = &stageX[wid][0];
    const float* Xh = Xw + h * 1024;
    const int gw = blockIdx.x * WPB + wid;
    float d2acc = 0.f;
    for (int mm = 0; mm < MPW; ++mm) {
        const size_t pairBase = ((size_t)(gw * MPW + mm)) * 2048;
        const float4* gx = reinterpret_cast<const float4*>(x + pairBase);
        float4* X4 = reinterpret_cast<float4*>(Xw);
#pragma unroll
        for (int ch = 0; ch < 8; ++ch) X4[ch * 64 + lane] = gx[ch * 64 + lane];
        float col[32];
        sxs_col(Xh, Sl, c, col);
        float nrm = colnorm(col);
        onesided_sweeps(col, nrm, NSWEEP_BATCH);
        nrm = colnorm(col);
#pragma unroll
        for (int i = 0; i < 32; ++i) outG[pairBase + h * 1024 + i * 32 + c] = col[i];
        float lg = 0.5f * logf(nrm);
        float l2 = lg * lg;
#pragma unroll
        for (int m = 1; m <= 32; m <<= 1) l2 += __shfl_xor(l2, m);
        d2acc += l2;
    }
    if (lane == 0) ws[WS_D2 + gw] = d2acc;
}

__global__ __launch_bounds__(256) void k_finish_p(float* __restrict__ ws,
                                                  const float* __restrict__ scale) {
    __shared__ float sm[256];
    int tid = threadIdx.x;
    float acc = 0.f;
    for (int g = tid; g < NW; g += 256) acc += ws[WS_D2 + g];
    sm[tid] = acc;
    __syncthreads();
    for (int off = 128; off > 0; off >>= 1) {
        if (tid < off) sm[tid] += sm[tid + off];
        __syncthreads();
    }
    if (tid == 0) {
        float sd = sqrtf(sm[0] / (float)BATCH);
        ws[WS_P] = scale[0] / (sd + EPSF);
    }
}

// ---------------- pass D: out = G diag(nrm^(p/2-1)) G^T ----------------

__global__ HEAVY_ATTRS void k_out_recon(float* __restrict__ outG,
                                        const float* __restrict__ ws) {
    __shared__ alignas(16) float stage[WPB][STG_F];
    const int tid = threadIdx.x;
    const int wid = tid >> 6, lane = tid & 63, h = lane >> 5, c = lane & 31;
    float* Gth = &stage[wid][h * GT_H];
    const float p = ws[WS_P];
    const float ex = 0.5f * p - 1.0f;                 // lam^p / lam^2
    const int gw = blockIdx.x * WPB + wid;
    for (int mm = 0; mm < MPW; ++mm) {
        const size_t pairBase = ((size_t)(gw * MPW + mm)) * 2048;
        float col[32];
#pragma unroll
        for (int i = 0; i < 32; ++i) col[i] = outG[pairBase + h * 1024 + i * 32 + c];
        float nrm = colnorm(col);
        stage_gt(Gth, c, col, expf(ex * logf(nrm)));
        float acc[32];
#pragma unroll
        for (int i = 0; i < 32; ++i) acc[i] = 0.f;
        recon_accum(Gth, c, acc);
#pragma unroll
        for (int i = 0; i < 32; ++i) outG[pairBase + h * 1024 + i * 32 + c] = acc[i];
    }
}

// ---------------- launch ----------------

extern "C" void kernel_launch(void* const* d_in, const int* in_sizes, int n_in,
                              void* d_out, int out_size, void* d_ws, size_t ws_size,
                              hipStream_t stream) {
    const float* x = (const float*)d_in[0];
    const float* scale = (const float*)d_in[1];
    float* out = (float*)d_out;
    float* ws = (float*)d_ws;
    const bool big = ws_size >= WS_NEED_BIG;

    // arithmetic mean -> M0
    k_mean_partial<<<G0, 256, 0, stream>>>(x, out);
    k_reduce_small<<<4, 256, 0, stream>>>(out, ws + WS_M0, G0, 1.0f / (float)BATCH);
    k_prep0<<<1, 64, 0, stream>>>(ws);
    // Karcher tangent mean: per-matrix logm into d_out, then reduce
    k_pass_logm<<<NBLK, NTHREADS, 0, stream>>>(x, ws, out);
    if (big) {
        k_mean_partial<<<G0, 256, 0, stream>>>(out, ws + WS_PART2);
        k_reduce_small<<<4, 256, 0, stream>>>(ws + WS_PART2, ws + WS_T, G0, 1.0f / (float)BATCH);
    } else {
        k_reduce_small<<<4, 256, 0, stream>>>(out, ws + WS_T, BATCH, 1.0f / (float)BATCH);
    }
    k_prep1<<<1, 64, 0, stream>>>(ws);
    // distance pass (+ store G)
    k_pass_dist<<<NBLK, NTHREADS, 0, stream>>>(x, ws, out);
    k_finish_p<<<1, 256, 0, stream>>>(ws, scale);
    // output
    k_out_recon<<<NBLK, NTHREADS, 0, stream>>>(out, ws);
}